// Round 12
// baseline (157.756 us; speedup 1.0000x reference)
//
#include <hip/hip_runtime.h>

// FastGaussianModel: values[m] = sum_n exp(-0.5 * sum_d (p[m,d]-q[n,d])^2 * iv[n,d]) * w[n]
//
// Round 12: fix R11's nondeterministic-worklist bug. R11 sliced a per-block
// worklist built by atomicAdd appends across grid.y blocks -- each block's
// list order differs, so index-sliced unions double-count/miss cells
// (absmax 1.19). Fix: NO worklist; deterministic partition by CELL INDEX
// (block y sweeps cells c == y mod 16, cull test inline, block-uniform ->
// wave-uniform branch). Pipeline unchanged: 8^3 counting sort of gaussians
// and points, block AABB shuffle-reduce, conservative ellipsoid box-box
// cull at 2^-20 (dropped mass <= ~5e-4), atomicAdd via original index in
// sortedPts.w. Dense fallback for non-shared scales kept.

constexpr int   CELLS  = 512;      // 8^3
constexpr int   GRID1D = 8;
constexpr float CELLH  = 0.125f;
constexpr int   NSLICE = 16;       // cell-index slices (grid.y of main)
constexpr int   BLOCK  = 128;      // main: 128 threads = 128 points, 2 waves
constexpr float TCUT   = -20.0f;   // exp2-domain cutoff (2^-20 ~ 1e-6)

__device__ __forceinline__ int cell_of(float x, float y, float z) {
    int cx = min(GRID1D - 1, max(0, (int)(x * GRID1D)));
    int cy = min(GRID1D - 1, max(0, (int)(y * GRID1D)));
    int cz = min(GRID1D - 1, max(0, (int)(z * GRID1D)));
    return (cx << 6) | (cy << 3) | cz;
}

// ---- k0: zero output + histograms ----
__global__ void fgm_zero(float* __restrict__ out, int out_n,
                         int* __restrict__ hists /*1024 ints*/) {
    int i = blockIdx.x * blockDim.x + threadIdx.x;
    int stride = gridDim.x * blockDim.x;
    for (int k = i; k < out_n; k += stride) out[k] = 0.f;
    for (int k = i; k < 2 * CELLS; k += stride) hists[k] = 0;
}

// ---- k1: histograms of gaussian cells and point cells ----
__global__ void fgm_hist(const float* __restrict__ points,
                         const float* __restrict__ positions,
                         int M, int N,
                         int* __restrict__ ghist, int* __restrict__ phist) {
    int i = blockIdx.x * blockDim.x + threadIdx.x;
    int stride = gridDim.x * blockDim.x;
    for (int n = i; n < N; n += stride) {
        int c = cell_of(positions[3*n], positions[3*n+1], positions[3*n+2]);
        atomicAdd(&ghist[c], 1);
    }
    for (int m = i; m < M; m += stride) {
        int c = cell_of(points[3*m], points[3*m+1], points[3*m+2]);
        atomicAdd(&phist[c], 1);
    }
}

// ---- k2: single block (512 thr): scans, gaussian coeff+scatter, header ----
__global__ void fgm_scan_scatter(const float* __restrict__ positions,
                                 const float* __restrict__ log_scales,
                                 const float* __restrict__ intensities,
                                 float* __restrict__ ws,        // header
                                 const int* __restrict__ ghist,
                                 const int* __restrict__ phist,
                                 int* __restrict__ gStart,      // 513
                                 int* __restrict__ pofs,        // 512
                                 float* __restrict__ fastT,     // 8*N
                                 float* __restrict__ fullT,     // 8*N
                                 int N) {
    __shared__ int sa[CELLS], sb[CELLS], gofs[CELLS];
    __shared__ int smism;
    int t = threadIdx.x;
    if (t == 0) smism = 0;

    // inclusive scan of ghist (Hillis-Steele, ping-pong)
    sa[t] = ghist[t];
    __syncthreads();
    int* src = sa; int* dst = sb;
    for (int off = 1; off < CELLS; off <<= 1) {
        int v = src[t];
        if (t >= off) v += src[t - off];
        dst[t] = v;
        __syncthreads();
        int* tmp = src; src = dst; dst = tmp;
    }
    int ginc = src[t];
    gStart[t + 1] = ginc;
    if (t == 0) gStart[0] = 0;
    gofs[t] = ginc - ghist[t];          // exclusive start
    __syncthreads();

    // inclusive scan of phist
    sa[t] = phist[t];
    __syncthreads();
    src = sa; dst = sb;
    for (int off = 1; off < CELLS; off <<= 1) {
        int v = src[t];
        if (t >= off) v += src[t - off];
        dst[t] = v;
        __syncthreads();
        int* tmp = src; src = dst; dst = tmp;
    }
    pofs[t] = src[t] - phist[t];        // exclusive start
    __syncthreads();

    // gaussian coefficients + scatter into cell-sorted order
    const float K = -0.7213475204444817f;  // -0.5 * log2(e)
    float r0 = K / (__expf(2.0f*log_scales[0]) + 1e-6f);
    float r1 = K / (__expf(2.0f*log_scales[1]) + 1e-6f);
    float r2 = K / (__expf(2.0f*log_scales[2]) + 1e-6f);

    int mism = 0;
    for (int n = t; n < N; n += blockDim.x) {
        float q0 = positions[3*n+0], q1 = positions[3*n+1], q2 = positions[3*n+2];
        float b0 = K / (__expf(2.0f*log_scales[3*n+0]) + 1e-6f);
        float b1 = K / (__expf(2.0f*log_scales[3*n+1]) + 1e-6f);
        float b2 = K / (__expf(2.0f*log_scales[3*n+2]) + 1e-6f);
        float a0 = -2.f*b0*q0, a1 = -2.f*b1*q1, a2 = -2.f*b2*q2;
        float c  = b0*q0*q0 + b1*q1*q1 + b2*q2*q2;   // <= 0 (K folded)
        float w  = intensities[n];
        if (b0 != r0 || b1 != r1 || b2 != r2) mism = 1;
        int cell = cell_of(q0, q1, q2);
        int slot = atomicAdd(&gofs[cell], 1);
        float4* f = (float4*)(fastT + (size_t)slot * 8);
        f[0] = make_float4(a0, a1, a2, c);
        f[1] = make_float4(w, 0.f, 0.f, 0.f);
        float4* o = (float4*)(fullT + (size_t)slot * 8);
        o[0] = make_float4(a0, a1, a2, b0);
        o[1] = make_float4(b1, b2, c, w);
    }
    if (mism) atomicOr(&smism, 1);
    __syncthreads();
    if (t == 0) {
        ws[0] = smism ? 1.f : 0.f;
        ws[1] = r0;  ws[2] = r1;  ws[3] = r2;
    }
}

// ---- k3: scatter points into cell-sorted order (orig index in .w) ----
__global__ void fgm_psort(const float* __restrict__ points, int M,
                          int* __restrict__ pofs,
                          float4* __restrict__ sortedPts) {
    int i = blockIdx.x * blockDim.x + threadIdx.x;
    int stride = gridDim.x * blockDim.x;
    for (int m = i; m < M; m += stride) {
        float x = points[3*m], y = points[3*m+1], z = points[3*m+2];
        int c = cell_of(x, y, z);
        int slot = atomicAdd(&pofs[c], 1);
        sortedPts[slot] = make_float4(x, y, z, __int_as_float(m));
    }
}

// ---- k4: main — 128 sorted points/block, deterministic cell slices ----
__global__ __launch_bounds__(BLOCK) void fgm_main(const float4* __restrict__ sortedPts,
                                                  const float* __restrict__ ws,
                                                  const int* __restrict__ gStart,
                                                  const float* __restrict__ fastT,
                                                  const float* __restrict__ fullT,
                                                  float* __restrict__ out,
                                                  int M, int N) {
    __shared__ float sbb[2][6];   // per-wave partial AABB

    int tid  = threadIdx.x;
    int lane = tid & 63;
    int wave = tid >> 6;
    int i = blockIdx.x * BLOCK + tid;

    bool fast = (ws[0] == 0.f);
    float r0 = ws[1], r1 = ws[2], r2 = ws[3];

    float px = 0.f, py = 0.f, pz = 0.f;
    int morig = -1;
    if (i < M) {
        float4 pr = sortedPts[i];
        px = pr.x; py = pr.y; pz = pr.z;
        morig = __float_as_int(pr.w);
    }
    float pp = r0*px*px + r1*py*py + r2*pz*pz;   // <= 0 seed (fast path)
    float acc = 0.f;

    if (fast) {
        // block AABB over active points (deterministic: same in every y-block)
        float lox = px, loy = py, loz = pz, hix = px, hiy = py, hiz = pz;
        if (i >= M) {
            lox = loy = loz =  1e30f;
            hix = hiy = hiz = -1e30f;
        }
        #pragma unroll
        for (int off = 32; off >= 1; off >>= 1) {
            lox = fminf(lox, __shfl_xor(lox, off));
            loy = fminf(loy, __shfl_xor(loy, off));
            loz = fminf(loz, __shfl_xor(loz, off));
            hix = fmaxf(hix, __shfl_xor(hix, off));
            hiy = fmaxf(hiy, __shfl_xor(hiy, off));
            hiz = fmaxf(hiz, __shfl_xor(hiz, off));
        }
        if (lane == 0) {
            sbb[wave][0] = lox; sbb[wave][1] = loy; sbb[wave][2] = loz;
            sbb[wave][3] = hix; sbb[wave][4] = hiy; sbb[wave][5] = hiz;
        }
        __syncthreads();
        lox = fminf(sbb[0][0], sbb[1][0]);
        loy = fminf(sbb[0][1], sbb[1][1]);
        loz = fminf(sbb[0][2], sbb[1][2]);
        hix = fmaxf(sbb[0][3], sbb[1][3]);
        hiy = fmaxf(sbb[0][4], sbb[1][4]);
        hiz = fmaxf(sbb[0][5], sbb[1][5]);

        // deterministic partition: this y-block owns cells c == blockIdx.y mod 16
        for (int c = blockIdx.y; c < CELLS; c += NSLICE) {
            int gLo = gStart[c], gHi = gStart[c + 1];
            if (gLo == gHi) continue;              // empty cell
            int cx = c >> 6, cy = (c >> 3) & 7, cz = c & 7;
            float cxl = cx * CELLH, cyl = cy * CELLH, czl = cz * CELLH;
            float dx = fmaxf(0.f, fmaxf(cxl - hix, lox - (cxl + CELLH)));
            float dy = fmaxf(0.f, fmaxf(cyl - hiy, loy - (cyl + CELLH)));
            float dz = fmaxf(0.f, fmaxf(czl - hiz, loz - (czl + CELLH)));
            float tmax = r0*dx*dx + r1*dy*dy + r2*dz*dz;   // r<=0 -> tmax<=0
            if (tmax < TCUT) continue;             // conservative cull
            for (int g = gLo; g < gHi; ++g) {
                const float4* rp = (const float4*)(fastT + (size_t)g * 8);
                float4 rA = rp[0];   // a0 a1 a2 c
                float4 rB = rp[1];   // w  -  -  -
                float t = rA.w + pp;
                t = __builtin_fmaf(rA.z, pz, t);
                t = __builtin_fmaf(rA.y, py, t);
                t = __builtin_fmaf(rA.x, px, t);
                acc = __builtin_fmaf(__builtin_amdgcn_exp2f(t), rB.x, acc);
            }
        }
    } else {
        // dense fallback: general per-gaussian scales, slice by gaussian index
        float qx = px*px, qy = py*py, qz = pz*pz;
        for (int g = blockIdx.y; g < N; g += NSLICE) {
            const float4* rp = (const float4*)(fullT + (size_t)g * 8);
            float4 rA = rp[0];   // a0 a1 a2 b0
            float4 rB = rp[1];   // b1 b2 c  w
            float t = __builtin_fmaf(rA.w, qx, rB.z);
            t = __builtin_fmaf(rB.x, qy, t);
            t = __builtin_fmaf(rB.y, qz, t);
            t = __builtin_fmaf(rA.z, pz, t);
            t = __builtin_fmaf(rA.y, py, t);
            t = __builtin_fmaf(rA.x, px, t);
            acc = __builtin_fmaf(__builtin_amdgcn_exp2f(t), rB.w, acc);
        }
    }

    if (i < M) atomicAdd(&out[morig], acc);
}

extern "C" void kernel_launch(void* const* d_in, const int* in_sizes, int n_in,
                              void* d_out, int out_size, void* d_ws, size_t ws_size,
                              hipStream_t stream) {
    const float* points      = (const float*)d_in[0];
    const float* positions   = (const float*)d_in[1];
    const float* log_scales  = (const float*)d_in[2];
    const float* intensities = (const float*)d_in[3];
    int M = in_sizes[0] / 3;
    int N = in_sizes[3];

    float* ws  = (float*)d_ws;
    int*   wsi = (int*)d_ws;
    // int region (after 16-float header)
    int* ghist  = wsi + 16;            // 512
    int* phist  = wsi + 528;           // 512
    int* gStart = wsi + 1040;          // 513
    int* pofs   = wsi + 1553;          // 512
    // float region (16B-aligned at float index 2080)
    float4* sortedPts = (float4*)(ws + 2080);              // M float4
    float*  fastT     = ws + 2080 + (size_t)4 * M;         // 8*N
    float*  fullT     = fastT + (size_t)8 * N;             // 8*N

    int zb = (max(out_size, 2 * CELLS) + 255) / 256;
    fgm_zero<<<zb, 256, 0, stream>>>((float*)d_out, out_size, ghist);

    int hb = (max(M, N) + 255) / 256;
    fgm_hist<<<hb, 256, 0, stream>>>(points, positions, M, N, ghist, phist);

    fgm_scan_scatter<<<1, CELLS, 0, stream>>>(positions, log_scales, intensities,
                                              ws, ghist, phist, gStart, pofs,
                                              fastT, fullT, N);

    fgm_psort<<<(M + 255) / 256, 256, 0, stream>>>(points, M, pofs, sortedPts);

    dim3 grid((M + BLOCK - 1) / BLOCK, NSLICE);
    fgm_main<<<grid, BLOCK, 0, stream>>>(sortedPts, ws, gStart, fastT, fullT,
                                         (float*)d_out, M, N);
}

// Round 13
// 75.372 us; speedup vs baseline: 2.0930x; 2.0930x over previous
//
#include <hip/hip_runtime.h>

// FastGaussianModel: values[m] = sum_n exp(-0.5 * sum_d (p[m,d]-q[n,d])^2 * iv[n,d]) * w[n]
//
// Round 13: back to dense (R10, best 74.09us). R12's cell-cull was correct
// but -83us: scattered per-permutation atomics (64 lines/wave), no-ILP
// per-cell loops, and a >=13us sort chain -- structurally unprofitable at
// N=1024. Final dense lever: wave residency. All dense variants ran ~6.1
// waves/SIMD; HW allows 8. SLICE_GROUPS 16->24 (48 slices, 11 pairs/slice)
// -> 4704 blocks / 9408 waves -> full 8 waves/SIMD residency.
// Everything else identical to R10: fast path (shared scales detected at
// runtime; t = C + pp + a.p inside exp2, all <= 0), 48 B/pair fast records,
// compile-time trip count, 2-wave blocks, 4 pts/lane, LDS 2-way fan-in +
// coalesced atomics into prep-zeroed out. Full-record fallback kept.

typedef float v2f __attribute__((ext_vector_type(2)));

constexpr int BLOCK         = 128;                  // 2 waves
constexpr int WAVES_PER_BLK = 2;
constexpr int PTS_PER_LANE  = 4;
constexpr int TILE_PTS      = 64 * PTS_PER_LANE;    // 256 points per block
constexpr int SLICE_GROUPS  = 24;                   // grid.y
constexpr int TOTAL_SLICES  = SLICE_GROUPS * WAVES_PER_BLK;  // 48
constexpr int HDR           = 16;                   // header floats
constexpr int FASTREC       = 12;                   // floats per fast pair rec (48 B)
constexpr int FULLREC       = 16;                   // floats per full pair rec (64 B)

// ws layout: [0..15] header (flag, b0, b1, b2, ...) |
//   fast table: NpairsPad * 12 floats [a0.xy a1.xy | a2.xy c.xy | w.xy pad2]
//   full table: NpairsPad * 16 floats [a0.xy a1.xy | a2.xy b0.xy |
//                                      b1.xy b2.xy | c.xy  w.xy]

// --- prep: single block; zeroes out, packs both tables, detects shared scales
__global__ void fgm_prep(const float* __restrict__ positions,
                         const float* __restrict__ log_scales,
                         const float* __restrict__ intensities,
                         float* __restrict__ ws,
                         float* __restrict__ out, int out_n,
                         int N, int NpairsPad) {
    __shared__ int smismatch;
    if (threadIdx.x == 0) smismatch = 0;
    __syncthreads();

    // zero the output (harness poisons it; main accumulates with atomics)
    {
        float4 z = make_float4(0.f, 0.f, 0.f, 0.f);
        float4* o4 = (float4*)out;
        int n4 = out_n >> 2;
        for (int i = threadIdx.x; i < n4; i += blockDim.x) o4[i] = z;
        for (int i = (n4 << 2) + threadIdx.x; i < out_n; i += blockDim.x) out[i] = 0.f;
    }

    const float K = -0.7213475204444817f;  // -0.5 * log2(e)
    float r0 = K / (__expf(2.0f*log_scales[0]) + 1e-6f);
    float r1 = K / (__expf(2.0f*log_scales[1]) + 1e-6f);
    float r2 = K / (__expf(2.0f*log_scales[2]) + 1e-6f);

    int mism = 0;
    float* fastT = ws + HDR;
    float* fullT = ws + HDR + (size_t)NpairsPad * FASTREC;
    for (int i = threadIdx.x; i < NpairsPad; i += blockDim.x) {
        float v[2][8];
        for (int h = 0; h < 2; ++h) {
            int n = 2*i + h;
            float a0=0.f,a1=0.f,a2=0.f,b0=0.f,b1=0.f,b2=0.f,c=0.f,w=0.f;
            if (n < N) {
                float q0 = positions[3*n+0], q1 = positions[3*n+1], q2 = positions[3*n+2];
                b0 = K / (__expf(2.0f*log_scales[3*n+0]) + 1e-6f);
                b1 = K / (__expf(2.0f*log_scales[3*n+1]) + 1e-6f);
                b2 = K / (__expf(2.0f*log_scales[3*n+2]) + 1e-6f);
                a0 = -2.f*b0*q0;  a1 = -2.f*b1*q1;  a2 = -2.f*b2*q2;
                c  = b0*q0*q0 + b1*q1*q1 + b2*q2*q2;   // <= 0 (K folded)
                w  = intensities[n];
                if (b0 != r0 || b1 != r1 || b2 != r2) mism = 1;
            }
            v[h][0]=a0; v[h][1]=a1; v[h][2]=a2; v[h][3]=b0;
            v[h][4]=b1; v[h][5]=b2; v[h][6]=c;  v[h][7]=w;
        }
        float4* f = (float4*)(fastT + (size_t)i * FASTREC);
        f[0] = make_float4(v[0][0], v[1][0], v[0][1], v[1][1]);  // a0.xy a1.xy
        f[1] = make_float4(v[0][2], v[1][2], v[0][6], v[1][6]);  // a2.xy c.xy
        f[2] = make_float4(v[0][7], v[1][7], 0.f,     0.f);      // w.xy  pad
        float4* o = (float4*)(fullT + (size_t)i * FULLREC);
        o[0] = make_float4(v[0][0], v[1][0], v[0][1], v[1][1]);
        o[1] = make_float4(v[0][2], v[1][2], v[0][3], v[1][3]);
        o[2] = make_float4(v[0][4], v[1][4], v[0][5], v[1][5]);
        o[3] = make_float4(v[0][6], v[1][6], v[0][7], v[1][7]);
    }
    if (mism) atomicOr(&smismatch, 1);
    __syncthreads();
    if (threadIdx.x == 0) {
        ws[0] = smismatch ? 1.f : 0.f;
        ws[1] = r0;  ws[2] = r1;  ws[3] = r2;
    }
}

// fast sweep: 48 B/pair; PAIRS>0 = compile-time trip count (full unroll)
template <int PAIRS>
__device__ __forceinline__ void sweep_fast(const v2f* __restrict__ cp, int pairs,
                                           const float* px, const float* py,
                                           const float* pz, const float* pp,
                                           v2f* acc) {
    const int n = PAIRS > 0 ? PAIRS : pairs;
    #pragma unroll
    for (int i = 0; i < n; ++i) {
        v2f A0 = cp[0], A1 = cp[1], A2 = cp[2], C = cp[3], W = cp[4];
        cp += 6;
        #pragma unroll
        for (int j = 0; j < PTS_PER_LANE; ++j) {
            v2f t = C + (v2f){pp[j], pp[j]};                    // <= ~0
            t = __builtin_elementwise_fma(A2, (v2f){pz[j], pz[j]}, t);
            t = __builtin_elementwise_fma(A1, (v2f){py[j], py[j]}, t);
            t = __builtin_elementwise_fma(A0, (v2f){px[j], px[j]}, t);
            v2f g;
            g.x = __builtin_amdgcn_exp2f(t.x);
            g.y = __builtin_amdgcn_exp2f(t.y);
            acc[j] = __builtin_elementwise_fma(g, W, acc[j]);
        }
    }
}

// fallback: full 64 B/pair records, general per-gaussian scales
__device__ __forceinline__ void sweep_full(const v2f* __restrict__ cp, int pairs,
                                           const float* px, const float* py,
                                           const float* pz, v2f* acc) {
    #pragma unroll 2
    for (int i = 0; i < pairs; ++i) {
        v2f A0 = cp[0], A1 = cp[1], A2 = cp[2];
        v2f B0 = cp[3], B1 = cp[4], B2 = cp[5];
        v2f C  = cp[6], W  = cp[7];
        cp += 8;
        #pragma unroll
        for (int j = 0; j < PTS_PER_LANE; ++j) {
            v2f t = __builtin_elementwise_fma(B0, (v2f){px[j]*px[j], px[j]*px[j]}, C);
            t = __builtin_elementwise_fma(B1, (v2f){py[j]*py[j], py[j]*py[j]}, t);
            t = __builtin_elementwise_fma(B2, (v2f){pz[j]*pz[j], pz[j]*pz[j]}, t);
            t = __builtin_elementwise_fma(A2, (v2f){pz[j], pz[j]}, t);
            t = __builtin_elementwise_fma(A1, (v2f){py[j], py[j]}, t);
            t = __builtin_elementwise_fma(A0, (v2f){px[j], px[j]}, t);
            v2f g;
            g.x = __builtin_amdgcn_exp2f(t.x);
            g.y = __builtin_amdgcn_exp2f(t.y);
            acc[j] = __builtin_elementwise_fma(g, W, acc[j]);
        }
    }
}

// --- main: 2 waves/block, 4 pts/lane, wave sweeps a PAIRS-pair slice ---
template <int PAIRS>
__global__ __launch_bounds__(BLOCK) void fgm_main(const float* __restrict__ points,
                                                  const float* __restrict__ ws,
                                                  float* __restrict__ out,
                                                  int M, int pairsPerSlice,
                                                  int NpairsPad) {
    __shared__ float red[WAVES_PER_BLK][TILE_PTS];  // 2 KB

    int lane = threadIdx.x & 63;
    int wave = __builtin_amdgcn_readfirstlane(threadIdx.x >> 6);
    int tileBase = blockIdx.x * TILE_PTS;
    int slice = blockIdx.y * WAVES_PER_BLK + wave;

    bool fast = (ws[0] == 0.f);
    float hb0 = ws[1], hb1 = ws[2], hb2 = ws[3];

    float px[PTS_PER_LANE], py[PTS_PER_LANE], pz[PTS_PER_LANE], pp[PTS_PER_LANE];
    v2f acc[PTS_PER_LANE];
    #pragma unroll
    for (int j = 0; j < PTS_PER_LANE; ++j) {
        int m = tileBase + lane + 64*j;
        float x = 0.f, y = 0.f, z = 0.f;
        if (m < M) { x = points[3*m+0]; y = points[3*m+1]; z = points[3*m+2]; }
        px[j] = x;  py[j] = y;  pz[j] = z;
        pp[j] = hb0*x*x + hb1*y*y + hb2*z*z;   // <= 0, per-point seed
        acc[j] = (v2f){0.f, 0.f};
    }

    if (fast) {
        const v2f* cp = (const v2f*)(ws + HDR) + (size_t)slice * pairsPerSlice * 6;
        sweep_fast<PAIRS>(cp, pairsPerSlice, px, py, pz, pp, acc);
    } else {
        const v2f* cp = (const v2f*)(ws + HDR + (size_t)NpairsPad * FASTREC)
                        + (size_t)slice * pairsPerSlice * 8;
        sweep_full(cp, pairsPerSlice, px, py, pz, acc);
    }

    #pragma unroll
    for (int j = 0; j < PTS_PER_LANE; ++j)
        red[wave][lane + 64*j] = acc[j].x + acc[j].y;
    __syncthreads();

    for (int p = threadIdx.x; p < TILE_PTS; p += BLOCK) {
        int m = tileBase + p;
        if (m < M) atomicAdd(&out[m], red[0][p] + red[1][p]);
    }
}

extern "C" void kernel_launch(void* const* d_in, const int* in_sizes, int n_in,
                              void* d_out, int out_size, void* d_ws, size_t ws_size,
                              hipStream_t stream) {
    const float* points      = (const float*)d_in[0];
    const float* positions   = (const float*)d_in[1];
    const float* log_scales  = (const float*)d_in[2];
    const float* intensities = (const float*)d_in[3];
    int M = in_sizes[0] / 3;
    int N = in_sizes[3];

    int Npairs        = (N + 1) / 2;
    int pairsPerSlice = (Npairs + TOTAL_SLICES - 1) / TOTAL_SLICES;   // 11 @ N=1024
    int NpairsPad     = pairsPerSlice * TOTAL_SLICES;                 // 528

    float* ws = (float*)d_ws;

    fgm_prep<<<1, 256, 0, stream>>>(positions, log_scales, intensities,
                                    ws, (float*)d_out, out_size, N, NpairsPad);

    int tiles = (M + TILE_PTS - 1) / TILE_PTS;   // 196
    dim3 grid(tiles, SLICE_GROUPS);               // 196 x 24, 2 waves/block
    if (pairsPerSlice == 11) {
        fgm_main<11><<<grid, BLOCK, 0, stream>>>(points, ws, (float*)d_out,
                                                 M, pairsPerSlice, NpairsPad);
    } else {
        fgm_main<0><<<grid, BLOCK, 0, stream>>>(points, ws, (float*)d_out,
                                                M, pairsPerSlice, NpairsPad);
    }
}